// Round 1
// baseline (4867.787 us; speedup 1.0000x reference)
//
#include <hip/hip_runtime.h>
#include <hip/hip_bf16.h>

#define NN 50000
#define RR 8
#define EE 200000
#define EDD 400000

// ---------------- degree histogram ----------------
__global__ void k_hist(const int* __restrict__ src, const int* __restrict__ dst,
                       int* __restrict__ outdeg, int* __restrict__ indeg) {
    int i = blockIdx.x * blockDim.x + threadIdx.x;
    if (i >= RR * EE) return;
    int r = i / EE;
    atomicAdd(&outdeg[r * NN + src[i]], 1);
    atomicAdd(&indeg[r * NN + dst[i]], 1);
}

// ---------------- norms from degrees ----------------
__global__ void k_norms(const int* __restrict__ outdeg, const int* __restrict__ indeg,
                        float* __restrict__ ns, float* __restrict__ nd) {
    int i = blockIdx.x * blockDim.x + threadIdx.x;
    if (i >= RR * NN) return;
    int od = outdeg[i];
    int id = indeg[i];
    ns[i] = od > 0 ? rsqrtf((float)od) : 0.f;
    nd[i] = id > 0 ? rsqrtf((float)id) : 0.f;
}

// ---------------- exclusive scan of indeg -> CSR offsets (one block per relation) ----------------
__global__ void k_scan(const int* __restrict__ indeg, int* __restrict__ offs) {
    int r = blockIdx.x;
    const int* in = indeg + (size_t)r * NN;
    int* out = offs + (size_t)r * (NN + 1);
    __shared__ int wsum[4];
    __shared__ int carry;
    if (threadIdx.x == 0) carry = 0;
    __syncthreads();
    int t = threadIdx.x, lane = t & 63, wid = t >> 6;
    for (int base = 0; base < NN; base += 256) {
        int i = base + t;
        int v = (i < NN) ? in[i] : 0;
        int sv = v;
        #pragma unroll
        for (int d = 1; d < 64; d <<= 1) {
            int u = __shfl_up(sv, d, 64);
            if (lane >= d) sv += u;
        }
        if (lane == 63) wsum[wid] = sv;
        __syncthreads();
        int add = carry;
        for (int w = 0; w < wid; w++) add += wsum[w];
        int incl = sv + add;
        if (i < NN) out[i] = incl - v;
        __syncthreads();
        if (t == 255) carry = incl;
        __syncthreads();
    }
    if (threadIdx.x == 0) out[NN] = carry;
}

// ---------------- fill CSR (dst-sorted src lists) ----------------
__global__ void k_fill(const int* __restrict__ src, const int* __restrict__ dst,
                       const int* __restrict__ offs, int* __restrict__ cursor,
                       int* __restrict__ csr) {
    int i = blockIdx.x * blockDim.x + threadIdx.x;
    if (i >= RR * EE) return;
    int r = i / EE;
    int d = dst[i];
    int pos = offs[r * (NN + 1) + d] + atomicAdd(&cursor[r * NN + d], 1);
    csr[(size_t)r * EE + pos] = src[i];
}

// ---------------- bias sums over relations ----------------
__global__ void k_bsum(const float* __restrict__ b2a, const float* __restrict__ b2b,
                       const float* __restrict__ b3a, const float* __restrict__ b3b,
                       float* __restrict__ bs) {
    int j = threadIdx.x;  // 256
    float s = 0.f;
    for (int r = 0; r < RR; r++) s += b2a[r * 256 + j];
    bs[j] = s;
    if (j < 128) {
        s = 0.f;
        for (int r = 0; r < RR; r++) s += b2b[r * 128 + j];
        bs[256 + j] = s;
    }
    s = 0.f;
    for (int r = 0; r < RR; r++) s += b3a[r * 256 + j];
    bs[512 + j] = s;
    if (j < 128) {
        s = 0.f;
        for (int r = 0; r < RR; r++) s += b3b[r * 128 + j];
        bs[768 + j] = s;
    }
}

// ---------------- init rows of C with a bias vector ----------------
__global__ void k_initrows(float* __restrict__ out, const float* __restrict__ bias,
                           int ncols, int ldc, int total) {
    int i = blockIdx.x * blockDim.x + threadIdx.x;
    if (i >= total) return;
    int n = i / ncols, j = i - n * ncols;
    out[(size_t)n * ldc + j] = bias[j];
}

// ---------------- aggregation: Y[n, :] = nd[n] * sum_{e in CSR(n)} ns[src_e] * x[src_e, :] ----------------
// thread j handles float4 chunk j; blockDim = nch rounded to 64
__global__ void k_agg4(const float* __restrict__ x, int xstride, int din4, int nch,
                       const int* __restrict__ csr, const int* __restrict__ offs,
                       const float* __restrict__ ns, const float* __restrict__ nd,
                       int r, float* __restrict__ Y, int ystride) {
    int n = blockIdx.x;
    int j = threadIdx.x;
    if (j >= nch) return;
    int o0 = offs[r * (NN + 1) + n];
    int o1 = offs[r * (NN + 1) + n + 1];
    float ndv = nd[(size_t)r * NN + n];
    const int* cs = csr + (size_t)r * EE;
    float ax = 0.f, ay = 0.f, az = 0.f, aw = 0.f;
    if (j < din4) {
        for (int e = o0; e < o1; e++) {
            int s = cs[e];
            float w = ns[(size_t)r * NN + s];
            const float4 v = *(const float4*)(x + (size_t)s * xstride + j * 4);
            ax += w * v.x; ay += w * v.y; az += w * v.z; aw += w * v.w;
        }
    }
    float4 o;
    o.x = ax * ndv; o.y = ay * ndv; o.z = az * ndv; o.w = aw * ndv;
    *(float4*)(Y + (size_t)n * ystride + j * 4) = o;
}

// ---------------- fp32 GEMM: C[M x Nout] += A[M x Kpad] * B[Kreal x Nout]; optional relu ----------------
__global__ __launch_bounds__(256) void k_gemm_acc(
        const float* __restrict__ A, int lda,
        const float* __restrict__ B, int ldb, int Kreal,
        float* __restrict__ C, int ldc,
        int M, int Kpad, int do_relu) {
    __shared__ float As[16][64];
    __shared__ float Bs[16][64];
    int m0 = blockIdx.x * 64;
    int n0 = blockIdx.y * 64;
    int t = threadIdx.x;
    int tx = t & 15, ty = t >> 4;
    int ar = t >> 2;         // 0..63  row in A tile
    int ac = (t & 3) * 4;    // 0,4,8,12 col in A tile
    int br = t >> 4;         // 0..15  k row in B tile
    int bc = (t & 15) * 4;   // 0..60  col in B tile
    float acc[4][4] = {{0.f}};
    for (int k0 = 0; k0 < Kpad; k0 += 16) {
        float4 av = {0.f, 0.f, 0.f, 0.f};
        if (m0 + ar < M) av = *(const float4*)(A + (size_t)(m0 + ar) * lda + k0 + ac);
        As[ac + 0][ar] = av.x;
        As[ac + 1][ar] = av.y;
        As[ac + 2][ar] = av.z;
        As[ac + 3][ar] = av.w;
        float4 bv = {0.f, 0.f, 0.f, 0.f};
        if (k0 + br < Kreal) bv = *(const float4*)(B + (size_t)(k0 + br) * ldb + n0 + bc);
        *(float4*)&Bs[br][bc] = bv;
        __syncthreads();
        #pragma unroll
        for (int k = 0; k < 16; k++) {
            float4 a = *(const float4*)&As[k][ty * 4];
            float4 b = *(const float4*)&Bs[k][tx * 4];
            acc[0][0] += a.x * b.x; acc[0][1] += a.x * b.y; acc[0][2] += a.x * b.z; acc[0][3] += a.x * b.w;
            acc[1][0] += a.y * b.x; acc[1][1] += a.y * b.y; acc[1][2] += a.y * b.z; acc[1][3] += a.y * b.w;
            acc[2][0] += a.z * b.x; acc[2][1] += a.z * b.y; acc[2][2] += a.z * b.z; acc[2][3] += a.z * b.w;
            acc[3][0] += a.w * b.x; acc[3][1] += a.w * b.y; acc[3][2] += a.w * b.z; acc[3][3] += a.w * b.w;
        }
        __syncthreads();
    }
    #pragma unroll
    for (int i = 0; i < 4; i++) {
        int m = m0 + ty * 4 + i;
        if (m < M) {
            float4* cp = (float4*)(C + (size_t)m * ldc + n0 + tx * 4);
            float4 cv = *cp;
            cv.x += acc[i][0]; cv.y += acc[i][1]; cv.z += acc[i][2]; cv.w += acc[i][3];
            if (do_relu) {
                cv.x = fmaxf(cv.x, 0.f); cv.y = fmaxf(cv.y, 0.f);
                cv.z = fmaxf(cv.z, 0.f); cv.w = fmaxf(cv.w, 0.f);
            }
            *cp = cv;
        }
    }
}

// ---------------- fused decoder weights: Mcat[256x16], cvec[8] ----------------
__global__ void k_mcat(const float* __restrict__ Wp1, const float* __restrict__ Wp2,
                       const float* __restrict__ bp1, const float* __restrict__ bp2,
                       float* __restrict__ Mcat, float* __restrict__ cvec) {
    int t = blockIdx.x * blockDim.x + threadIdx.x;
    if (t < 4096) {
        int i = t >> 4, j = t & 15;
        int half = j >> 3, jj = j & 7;
        const float* wrow = Wp1 + (size_t)(half * 256 + i) * 256;
        float s = 0.f;
        for (int k = 0; k < 256; k++) s += wrow[k] * Wp2[k * 8 + jj];
        Mcat[i * 16 + j] = s;
    } else if (t < 4096 + 8) {
        int j = t - 4096;
        float s = bp2[j];
        for (int k = 0; k < 256; k++) s += bp1[k] * Wp2[k * 8 + j];
        cvec[j] = s;
    }
}

// ---------------- AB = feat @ Mcat  [N x 16] ----------------
__global__ void k_ab(const float* __restrict__ feat, const float* __restrict__ Mcat,
                     float* __restrict__ AB) {
    __shared__ float Ms[4096];
    int t = threadIdx.x;
    for (int i = t; i < 4096; i += 256) Ms[i] = Mcat[i];
    __syncthreads();
    int n = blockIdx.x * 16 + (t >> 4);
    int c = t & 15;
    const float* fr = feat + (size_t)n * 256;
    float s = 0.f;
    for (int k = 0; k < 256; k++) s += fr[k] * Ms[k * 16 + c];
    AB[(size_t)n * 16 + c] = s;
}

// ---------------- per-edge decoder: out[e,k] = AB[s,k] + AB[d,8+k] + c[k] ----------------
__global__ void k_dec(const int* __restrict__ dsrc, const int* __restrict__ ddst,
                      const float* __restrict__ AB, const float* __restrict__ cvec,
                      float* __restrict__ out) {
    int i = blockIdx.x * blockDim.x + threadIdx.x;
    if (i >= EDD * 8) return;
    int e = i >> 3, k = i & 7;
    out[i] = AB[dsrc[e] * 16 + k] + AB[ddst[e] * 16 + 8 + k] + cvec[k];
}

extern "C" void kernel_launch(void* const* d_in, const int* in_sizes, int n_in,
                              void* d_out, int out_size, void* d_ws, size_t ws_size,
                              hipStream_t stream) {
    const float* x2  = (const float*)d_in[0];
    const float* x3  = (const float*)d_in[1];
    const int*   src = (const int*)d_in[2];
    const int*   dst = (const int*)d_in[3];
    const int*   dsrc = (const int*)d_in[4];
    const int*   ddst = (const int*)d_in[5];
    const float* W2a = (const float*)d_in[6];
    const float* b2a = (const float*)d_in[7];
    const float* W2b = (const float*)d_in[8];
    const float* b2b = (const float*)d_in[9];
    const float* W3a = (const float*)d_in[10];
    const float* b3a = (const float*)d_in[11];
    const float* W3b = (const float*)d_in[12];
    const float* b3b = (const float*)d_in[13];
    const float* Wp1 = (const float*)d_in[14];
    const float* bp1 = (const float*)d_in[15];
    const float* Wp2 = (const float*)d_in[16];
    const float* bp2 = (const float*)d_in[17];
    float* out = (float*)d_out;

    char* ws = (char*)d_ws;
    size_t off = 0;
    auto alloc = [&](size_t nbytes) {
        char* p = ws + off;
        off += nbytes;
        off = (off + 255) & ~(size_t)255;
        return p;
    };
    int*   outdeg = (int*)alloc((size_t)RR * NN * 4);
    int*   indeg  = (int*)alloc((size_t)RR * NN * 4);
    int*   offs   = (int*)alloc((size_t)RR * (NN + 1) * 4);
    int*   cursor = (int*)alloc((size_t)RR * NN * 4);
    int*   csr    = (int*)alloc((size_t)RR * EE * 4);
    float* ns     = (float*)alloc((size_t)RR * NN * 4);
    float* nd     = (float*)alloc((size_t)RR * NN * 4);
    float* Y      = (float*)alloc((size_t)NN * 304 * 4);
    float* hbuf   = (float*)alloc((size_t)NN * 256 * 4);
    float* feat   = (float*)alloc((size_t)NN * 256 * 4);
    float* bsums  = (float*)alloc(1024 * 4);
    float* Mcat   = (float*)alloc(4096 * 4);
    float* cvec   = (float*)alloc(64 * 4);
    float* AB     = (float*)alloc((size_t)NN * 16 * 4);

    // ---- graph prep ----
    hipMemsetAsync(outdeg, 0, (size_t)RR * NN * 4, stream);
    hipMemsetAsync(indeg,  0, (size_t)RR * NN * 4, stream);
    hipMemsetAsync(cursor, 0, (size_t)RR * NN * 4, stream);

    int histBlocks = (RR * EE + 255) / 256;
    k_hist<<<histBlocks, 256, 0, stream>>>(src, dst, outdeg, indeg);
    int normBlocks = (RR * NN + 255) / 256;
    k_norms<<<normBlocks, 256, 0, stream>>>(outdeg, indeg, ns, nd);
    k_scan<<<RR, 256, 0, stream>>>(indeg, offs);
    k_fill<<<histBlocks, 256, 0, stream>>>(src, dst, offs, cursor, csr);
    k_bsum<<<1, 256, 0, stream>>>(b2a, b2b, b3a, b3b, bsums);
    k_mcat<<<17, 256, 0, stream>>>(Wp1, Wp2, bp1, bp2, Mcat, cvec);

    dim3 gemmGridA((NN + 63) / 64, 4);  // Nout=256
    dim3 gemmGridB((NN + 63) / 64, 2);  // Nout=128

    // ---- layer 2 (node2_features, din 256) ----
    k_initrows<<<(NN * 256 + 255) / 256, 256, 0, stream>>>(hbuf, bsums + 0, 256, 256, NN * 256);
    for (int r = 0; r < RR; r++) {
        k_agg4<<<NN, 64, 0, stream>>>(x2, 256, 64, 64, csr, offs, ns, nd, r, Y, 256);
        k_gemm_acc<<<gemmGridA, 256, 0, stream>>>(Y, 256, W2a + (size_t)r * 256 * 256, 256, 256,
                                                  hbuf, 256, NN, 256, (r == RR - 1) ? 1 : 0);
    }
    k_initrows<<<(NN * 128 + 255) / 256, 256, 0, stream>>>(feat, bsums + 256, 128, 256, NN * 128);
    for (int r = 0; r < RR; r++) {
        k_agg4<<<NN, 64, 0, stream>>>(hbuf, 256, 64, 64, csr, offs, ns, nd, r, Y, 256);
        k_gemm_acc<<<gemmGridB, 256, 0, stream>>>(Y, 256, W2b + (size_t)r * 256 * 128, 128, 256,
                                                  feat, 256, NN, 256, 0);
    }

    // ---- layer 3 (mpnn_features, din 300 -> pad 304) ----
    k_initrows<<<(NN * 256 + 255) / 256, 256, 0, stream>>>(hbuf, bsums + 512, 256, 256, NN * 256);
    for (int r = 0; r < RR; r++) {
        k_agg4<<<NN, 128, 0, stream>>>(x3, 300, 75, 76, csr, offs, ns, nd, r, Y, 304);
        k_gemm_acc<<<gemmGridA, 256, 0, stream>>>(Y, 304, W3a + (size_t)r * 300 * 256, 256, 300,
                                                  hbuf, 256, NN, 304, (r == RR - 1) ? 1 : 0);
    }
    k_initrows<<<(NN * 128 + 255) / 256, 256, 0, stream>>>(feat + 128, bsums + 768, 128, 256, NN * 128);
    for (int r = 0; r < RR; r++) {
        k_agg4<<<NN, 64, 0, stream>>>(hbuf, 256, 64, 64, csr, offs, ns, nd, r, Y, 256);
        k_gemm_acc<<<gemmGridB, 256, 0, stream>>>(Y, 256, W3b + (size_t)r * 256 * 128, 128, 256,
                                                  feat + 128, 256, NN, 256, 0);
    }

    // ---- decoder ----
    k_ab<<<NN / 16, 256, 0, stream>>>(feat, Mcat, AB);
    k_dec<<<(EDD * 8 + 255) / 256, 256, 0, stream>>>(dsrc, ddst, AB, cvec, out);
}

// Round 3
// 2157.306 us; speedup vs baseline: 2.2564x; 2.2564x over previous
//
#include <hip/hip_runtime.h>
#include <hip/hip_bf16.h>

#define NN 50000
#define RR 8
#define EE 200000
#define EDD 400000

typedef __attribute__((ext_vector_type(8))) short short8;
typedef __attribute__((ext_vector_type(4))) float floatx4;

static __device__ __forceinline__ unsigned short f2bf(float f) {
    union { float f; unsigned u; } v; v.f = f;
    unsigned r = v.u + 0x7fff + ((v.u >> 16) & 1);
    return (unsigned short)(r >> 16);
}
static __device__ __forceinline__ float bf2f(unsigned short h) {
    union { unsigned u; float f; } v; v.u = ((unsigned)h) << 16;
    return v.f;
}

// ---------------- degree histogram ----------------
__global__ void k_hist(const int* __restrict__ src, const int* __restrict__ dst,
                       int* __restrict__ outdeg, int* __restrict__ indeg) {
    int i = blockIdx.x * blockDim.x + threadIdx.x;
    if (i >= RR * EE) return;
    int r = i / EE;
    atomicAdd(&outdeg[r * NN + src[i]], 1);
    atomicAdd(&indeg[r * NN + dst[i]], 1);
}

// ---------------- norms: in-place int degree -> float rsqrt ----------------
__global__ void k_norms(int* __restrict__ outdeg, int* __restrict__ indeg) {
    int i = blockIdx.x * blockDim.x + threadIdx.x;
    if (i >= RR * NN) return;
    int od = outdeg[i];
    int id = indeg[i];
    ((float*)outdeg)[i] = od > 0 ? rsqrtf((float)od) : 0.f;
    ((float*)indeg)[i]  = id > 0 ? rsqrtf((float)id) : 0.f;
}

// ---------------- exclusive scan of indeg -> CSR offsets ----------------
__global__ void k_scan(const int* __restrict__ indeg, int* __restrict__ offs) {
    int r = blockIdx.x;
    const int* in = indeg + (size_t)r * NN;
    int* out = offs + (size_t)r * (NN + 1);
    __shared__ int wsum[4];
    __shared__ int carry;
    if (threadIdx.x == 0) carry = 0;
    __syncthreads();
    int t = threadIdx.x, lane = t & 63, wid = t >> 6;
    for (int base = 0; base < NN; base += 256) {
        int i = base + t;
        int v = (i < NN) ? in[i] : 0;
        int sv = v;
        #pragma unroll
        for (int d = 1; d < 64; d <<= 1) {
            int u = __shfl_up(sv, d, 64);
            if (lane >= d) sv += u;
        }
        if (lane == 63) wsum[wid] = sv;
        __syncthreads();
        int add = carry;
        for (int w = 0; w < wid; w++) add += wsum[w];
        int incl = sv + add;
        if (i < NN) out[i] = incl - v;
        __syncthreads();
        if (t == 255) carry = incl;
        __syncthreads();
    }
    if (threadIdx.x == 0) out[NN] = carry;
}

// ---------------- fill CSR ----------------
__global__ void k_fill(const int* __restrict__ src, const int* __restrict__ dst,
                       const int* __restrict__ offs, int* __restrict__ cursor,
                       int* __restrict__ csr) {
    int i = blockIdx.x * blockDim.x + threadIdx.x;
    if (i >= RR * EE) return;
    int r = i / EE;
    int d = dst[i];
    int pos = offs[r * (NN + 1) + d] + atomicAdd(&cursor[r * NN + d], 1);
    csr[(size_t)r * EE + pos] = src[i];
}

// ---------------- bias sums over relations ----------------
__global__ void k_bsum(const float* __restrict__ b2a, const float* __restrict__ b2b,
                       const float* __restrict__ b3a, const float* __restrict__ b3b,
                       float* __restrict__ bs) {
    int j = threadIdx.x;  // 256
    float s = 0.f;
    for (int r = 0; r < RR; r++) s += b2a[r * 256 + j];
    bs[j] = s;
    if (j < 128) {
        s = 0.f;
        for (int r = 0; r < RR; r++) s += b2b[r * 128 + j];
        bs[256 + j] = s;
    }
    s = 0.f;
    for (int r = 0; r < RR; r++) s += b3a[r * 256 + j];
    bs[512 + j] = s;
    if (j < 128) {
        s = 0.f;
        for (int r = 0; r < RR; r++) s += b3b[r * 128 + j];
        bs[768 + j] = s;
    }
}

// ---------------- fp32 -> bf16 elementwise cast ----------------
__global__ void k_cast(const float* __restrict__ x, unsigned short* __restrict__ y, int total) {
    int i = blockIdx.x * blockDim.x + threadIdx.x;
    if (i < total) y[i] = f2bf(x[i]);
}

// ---------------- weights: W[R,K0,Nout] -> WT[Nout][R*Kpad] bf16 (transposed, k-padded) ----------------
__global__ void k_wt(const float* __restrict__ W, unsigned short* __restrict__ WT,
                     int K0, int Kpad, int Nout) {
    int i = blockIdx.x * blockDim.x + threadIdx.x;
    int total = Nout * RR * Kpad;
    if (i >= total) return;
    int n = i / (RR * Kpad);
    int rem = i - n * (RR * Kpad);
    int r = rem / Kpad;
    int k = rem - r * Kpad;
    float v = (k < K0) ? W[((size_t)r * K0 + k) * Nout + n] : 0.f;
    WT[i] = f2bf(v);
}

// ---------------- aggregation: Y[n-nbase][by*Kpad + j*4..] = nd*sum ns[s]*x[s, j*4..] ----------------
__global__ void k_agg(const unsigned short* __restrict__ xb, int xstride, int din4, int nch,
                      const int* __restrict__ csr, const int* __restrict__ offs,
                      const float* __restrict__ ns, const float* __restrict__ nd,
                      int rbase, int nbase, unsigned short* __restrict__ Y,
                      int Kpad, int ystride) {
    int n = nbase + blockIdx.x;
    int r = rbase + blockIdx.y;
    int j = threadIdx.x;
    if (j >= nch) return;
    int o0 = offs[r * (NN + 1) + n];
    int o1 = offs[r * (NN + 1) + n + 1];
    float ndv = nd[(size_t)r * NN + n];
    const int* cs = csr + (size_t)r * EE;
    float a0 = 0.f, a1 = 0.f, a2 = 0.f, a3 = 0.f;
    if (j < din4) {
        for (int e = o0; e < o1; e++) {
            int s = cs[e];
            float w = ns[(size_t)r * NN + s];
            ushort4 v = *(const ushort4*)(xb + (size_t)s * xstride + j * 4);
            a0 += w * bf2f(v.x); a1 += w * bf2f(v.y);
            a2 += w * bf2f(v.z); a3 += w * bf2f(v.w);
        }
    }
    ushort4 o;
    o.x = f2bf(a0 * ndv); o.y = f2bf(a1 * ndv);
    o.z = f2bf(a2 * ndv); o.w = f2bf(a3 * ndv);
    *(ushort4*)(Y + (size_t)blockIdx.x * ystride + (size_t)blockIdx.y * Kpad + j * 4) = o;
}

// ---------------- bf16 MFMA GEMM: out = [Cin +] [bias +] A@BT^T, opt relu, opt bf16 out ----------------
// A [M x K] bf16 (lda), BT [Nout x K] bf16 (ldb). 128x128 tile, BK=64.
// flags: 1=addbias, 2=accum(read Cin fp32), 4=relu, 8=out bf16 (else fp32)
#define LSTR 72
__global__ __launch_bounds__(256) void k_gemm_bf(
        const unsigned short* __restrict__ A, int lda,
        const unsigned short* __restrict__ BT, int ldb,
        const float* __restrict__ bias,
        const float* __restrict__ Cin, int ldcin,
        void* __restrict__ Cout, int ldc,
        int M, int K, int flags) {
    __shared__ unsigned short As[128 * LSTR];
    __shared__ unsigned short Bs[128 * LSTR];
    int m0 = blockIdx.x * 128;
    int n0 = blockIdx.y * 128;
    int t = threadIdx.x;
    int w = t >> 6, l = t & 63;
    int qm = (w >> 1) * 64, qn = (w & 1) * 64;
    int lr = l & 15, lg = l >> 4;

    floatx4 acc[4][4];
    #pragma unroll
    for (int a = 0; a < 4; a++)
        #pragma unroll
        for (int b = 0; b < 4; b++)
            acc[a][b] = (floatx4){0.f, 0.f, 0.f, 0.f};

    for (int k0 = 0; k0 < K; k0 += 64) {
        #pragma unroll
        for (int i = 0; i < 4; i++) {
            int c = t + i * 256;          // 1024 chunks of 8 bf16
            int row = c >> 3;
            int col = (c & 7) << 3;
            int gr = m0 + row; if (gr > M - 1) gr = M - 1;
            *(short8*)&As[row * LSTR + col] =
                *(const short8*)(A + (size_t)gr * lda + k0 + col);
            *(short8*)&Bs[row * LSTR + col] =
                *(const short8*)(BT + (size_t)(n0 + row) * ldb + k0 + col);
        }
        __syncthreads();
        #pragma unroll
        for (int ks = 0; ks < 2; ks++) {
            int kb = ks * 32 + lg * 8;
            short8 af[4], bf[4];
            #pragma unroll
            for (int i = 0; i < 4; i++) {
                af[i] = *(const short8*)&As[(qm + i * 16 + lr) * LSTR + kb];
                bf[i] = *(const short8*)&Bs[(qn + i * 16 + lr) * LSTR + kb];
            }
            #pragma unroll
            for (int tm = 0; tm < 4; tm++)
                #pragma unroll
                for (int tn = 0; tn < 4; tn++)
                    acc[tm][tn] = __builtin_amdgcn_mfma_f32_16x16x32_bf16(
                        af[tm], bf[tn], acc[tm][tn], 0, 0, 0);
        }
        __syncthreads();
    }

    int addbias = flags & 1, accum = flags & 2, relu = flags & 4, outbf = flags & 8;
    #pragma unroll
    for (int tm = 0; tm < 4; tm++) {
        int rbase = m0 + qm + tm * 16 + lg * 4;
        #pragma unroll
        for (int reg = 0; reg < 4; reg++) {
            int row = rbase + reg;
            if (row >= M) continue;
            #pragma unroll
            for (int tn = 0; tn < 4; tn++) {
                int col = n0 + qn + tn * 16 + lr;
                float v = acc[tm][tn][reg];
                if (addbias) v += bias[col];
                if (accum) v += Cin[(size_t)row * ldcin + col];
                if (relu) v = fmaxf(v, 0.f);
                if (outbf) ((unsigned short*)Cout)[(size_t)row * ldc + col] = f2bf(v);
                else       ((float*)Cout)[(size_t)row * ldc + col] = v;
            }
        }
    }
}

// ---------------- fused decoder weights ----------------
__global__ void k_mcat(const float* __restrict__ Wp1, const float* __restrict__ Wp2,
                       const float* __restrict__ bp1, const float* __restrict__ bp2,
                       float* __restrict__ Mcat, float* __restrict__ cvec) {
    int t = blockIdx.x * blockDim.x + threadIdx.x;
    if (t < 4096) {
        int i = t >> 4, j = t & 15;
        int half = j >> 3, jj = j & 7;
        const float* wrow = Wp1 + (size_t)(half * 256 + i) * 256;
        float s = 0.f;
        for (int k = 0; k < 256; k++) s += wrow[k] * Wp2[k * 8 + jj];
        Mcat[i * 16 + j] = s;
    } else if (t < 4096 + 8) {
        int j = t - 4096;
        float s = bp2[j];
        for (int k = 0; k < 256; k++) s += bp1[k] * Wp2[k * 8 + j];
        cvec[j] = s;
    }
}

// ---------------- AB = feat @ Mcat  [N x 16] ----------------
__global__ void k_ab(const float* __restrict__ feat, const float* __restrict__ Mcat,
                     float* __restrict__ AB) {
    __shared__ float Ms[4096];
    int t = threadIdx.x;
    for (int i = t; i < 4096; i += 256) Ms[i] = Mcat[i];
    __syncthreads();
    int n = blockIdx.x * 16 + (t >> 4);
    int c = t & 15;
    const float* fr = feat + (size_t)n * 256;
    float s = 0.f;
    for (int k = 0; k < 256; k++) s += fr[k] * Ms[k * 16 + c];
    AB[(size_t)n * 16 + c] = s;
}

// ---------------- per-edge decoder ----------------
__global__ void k_dec(const int* __restrict__ dsrc, const int* __restrict__ ddst,
                      const float* __restrict__ AB, const float* __restrict__ cvec,
                      float* __restrict__ out) {
    int i = blockIdx.x * blockDim.x + threadIdx.x;
    if (i >= EDD * 8) return;
    int e = i >> 3, k = i & 7;
    out[i] = AB[dsrc[e] * 16 + k] + AB[ddst[e] * 16 + 8 + k] + cvec[k];
}

extern "C" void kernel_launch(void* const* d_in, const int* in_sizes, int n_in,
                              void* d_out, int out_size, void* d_ws, size_t ws_size,
                              hipStream_t stream) {
    const float* x2  = (const float*)d_in[0];
    const float* x3  = (const float*)d_in[1];
    const int*   src = (const int*)d_in[2];
    const int*   dst = (const int*)d_in[3];
    const int*   dsrc = (const int*)d_in[4];
    const int*   ddst = (const int*)d_in[5];
    const float* W2a = (const float*)d_in[6];
    const float* b2a = (const float*)d_in[7];
    const float* W2b = (const float*)d_in[8];
    const float* b2b = (const float*)d_in[9];
    const float* W3a = (const float*)d_in[10];
    const float* b3a = (const float*)d_in[11];
    const float* W3b = (const float*)d_in[12];
    const float* b3b = (const float*)d_in[13];
    const float* Wp1 = (const float*)d_in[14];
    const float* bp1 = (const float*)d_in[15];
    const float* Wp2 = (const float*)d_in[16];
    const float* bp2 = (const float*)d_in[17];
    float* out = (float*)d_out;

    // ---- workspace layout (total ~181.8 MB, < round-1's proven 182.4 MB) ----
    char* ws = (char*)d_ws;
    size_t off = 0;
    auto alloc = [&](size_t nbytes) {
        char* p = ws + off;
        off += nbytes;
        off = (off + 255) & ~(size_t)255;
        return p;
    };
    float* ns   = (float*)alloc((size_t)RR * NN * 4);        // also outdeg (int) before k_norms
    float* nd   = (float*)alloc((size_t)RR * NN * 4);        // also indeg (int) before k_norms
    int*   offs = (int*)alloc((size_t)RR * (NN + 1) * 4);
    int*   csr  = (int*)alloc((size_t)RR * EE * 4);
    unsigned short* XH   = (unsigned short*)alloc((size_t)NN * 300 * 2);  // x2b then x3b
    unsigned short* hbuf = (unsigned short*)alloc((size_t)NN * 256 * 2);  // layer-a out; AB aliases
    unsigned short* WT2a = (unsigned short*)alloc((size_t)256 * 2048 * 2);
    unsigned short* WT2b = (unsigned short*)alloc((size_t)128 * 2048 * 2);
    unsigned short* WT3a = (unsigned short*)alloc((size_t)256 * 2432 * 2);
    unsigned short* WT3b = (unsigned short*)alloc((size_t)128 * 2048 * 2);
    unsigned short* Y    = (unsigned short*)alloc((size_t)12500 * 2432 * 2);  // also L-b Y [50000x512]; cursor aliases head
    float* feat  = (float*)alloc((size_t)NN * 256 * 4);
    float* bsums = (float*)alloc(1024 * 4);
    float* Mcat  = (float*)alloc(4096 * 4);
    float* cvec  = (float*)alloc(64 * 4);

    int*   outdeg = (int*)ns;
    int*   indeg  = (int*)nd;
    int*   cursor = (int*)Y;       // used only during k_fill (before any Y use)
    float* AB     = (float*)hbuf;  // used only after last hbuf read

    // ---- graph prep ----
    hipMemsetAsync(outdeg, 0, (size_t)RR * NN * 4, stream);
    hipMemsetAsync(indeg,  0, (size_t)RR * NN * 4, stream);
    hipMemsetAsync(cursor, 0, (size_t)RR * NN * 4, stream);

    int histBlocks = (RR * EE + 255) / 256;
    k_hist<<<histBlocks, 256, 0, stream>>>(src, dst, outdeg, indeg);
    k_scan<<<RR, 256, 0, stream>>>(indeg, offs);          // must precede k_norms (in-place)
    k_norms<<<(RR * NN + 255) / 256, 256, 0, stream>>>(outdeg, indeg);
    k_fill<<<histBlocks, 256, 0, stream>>>(src, dst, offs, cursor, csr);
    k_bsum<<<1, 256, 0, stream>>>(b2a, b2b, b3a, b3b, bsums);
    k_mcat<<<17, 256, 0, stream>>>(Wp1, Wp2, bp1, bp2, Mcat, cvec);

    k_cast<<<(NN * 256 + 255) / 256, 256, 0, stream>>>(x2, XH, NN * 256);
    k_wt<<<(256 * RR * 256 + 255) / 256, 256, 0, stream>>>(W2a, WT2a, 256, 256, 256);
    k_wt<<<(128 * RR * 256 + 255) / 256, 256, 0, stream>>>(W2b, WT2b, 256, 256, 128);
    k_wt<<<(256 * RR * 304 + 255) / 256, 256, 0, stream>>>(W3a, WT3a, 300, 304, 256);
    k_wt<<<(128 * RR * 256 + 255) / 256, 256, 0, stream>>>(W3b, WT3b, 256, 256, 128);

    const int CH = 12500;                 // node chunk for layer-a (4 chunks)
    dim3 gChunkA((CH + 127) / 128, 2);    // layer-a GEMM: Nout=256
    dim3 gFullB((NN + 127) / 128, 1);     // layer-b GEMM: Nout=128

    // ---- layer 2a: hbuf = relu(sum_r agg_r(x2b) @ W2a_r + b) ----
    for (int c = 0; c < 4; c++) {
        int nb = c * CH;
        k_agg<<<dim3(CH, 8), 64, 0, stream>>>(XH, 256, 64, 64, csr, offs, ns, nd,
                                              0, nb, Y, 256, 2048);
        k_gemm_bf<<<gChunkA, 256, 0, stream>>>(Y, 2048, WT2a, 2048, bsums + 0,
                                               feat, 256, (void*)(hbuf + (size_t)nb * 256), 256,
                                               CH, 2048, 1 | 4 | 8);
    }
    // ---- layer 2b: feat[:, :128] = sum_r agg_r(hbuf) @ W2b_r + b ----
    for (int p = 0; p < 4; p++) {
        k_agg<<<dim3(NN, 2), 64, 0, stream>>>(hbuf, 256, 64, 64, csr, offs, ns, nd,
                                              p * 2, 0, Y, 256, 512);
        k_gemm_bf<<<gFullB, 256, 0, stream>>>(Y, 512, WT2b + (size_t)p * 512, 2048,
                                              bsums + 256, feat, 256, (void*)feat, 256,
                                              NN, 512, (p == 0) ? 1 : 2);
    }
    // ---- layer 3a (x3: din 300) ----
    k_cast<<<(NN * 300 + 255) / 256, 256, 0, stream>>>(x3, XH, NN * 300);
    for (int c = 0; c < 4; c++) {
        int nb = c * CH;
        k_agg<<<dim3(CH, 8), 128, 0, stream>>>(XH, 300, 75, 76, csr, offs, ns, nd,
                                               0, nb, Y, 304, 2432);
        k_gemm_bf<<<gChunkA, 256, 0, stream>>>(Y, 2432, WT3a, 2432, bsums + 512,
                                               feat, 256, (void*)(hbuf + (size_t)nb * 256), 256,
                                               CH, 2432, 1 | 4 | 8);
    }
    // ---- layer 3b: feat[:, 128:] ----
    for (int p = 0; p < 4; p++) {
        k_agg<<<dim3(NN, 2), 64, 0, stream>>>(hbuf, 256, 64, 64, csr, offs, ns, nd,
                                              p * 2, 0, Y, 256, 512);
        k_gemm_bf<<<gFullB, 256, 0, stream>>>(Y, 512, WT3b + (size_t)p * 512, 2048,
                                              bsums + 768, feat + 128, 256, (void*)(feat + 128), 256,
                                              NN, 512, (p == 0) ? 1 : 2);
    }

    // ---- decoder ----
    k_ab<<<NN / 16, 256, 0, stream>>>(feat, Mcat, AB);
    k_dec<<<(EDD * 8 + 255) / 256, 256, 0, stream>>>(dsrc, ddst, AB, cvec, out);
}

// Round 4
// 1962.176 us; speedup vs baseline: 2.4808x; 1.0994x over previous
//
#include <hip/hip_runtime.h>
#include <hip/hip_bf16.h>

#define NN 50000
#define RR 8
#define EE 200000
#define EDD 400000
#define SCB 196   // ceil(NN/256) scan blocks

typedef __attribute__((ext_vector_type(8))) short short8;
typedef __attribute__((ext_vector_type(4))) float floatx4;

static __device__ __forceinline__ unsigned short f2bf(float f) {
    union { float f; unsigned u; } v; v.f = f;
    unsigned r = v.u + 0x7fff + ((v.u >> 16) & 1);
    return (unsigned short)(r >> 16);
}
static __device__ __forceinline__ float bf2f(unsigned short h) {
    union { unsigned u; float f; } v; v.u = ((unsigned)h) << 16;
    return v.f;
}
// async global->LDS, 16B per lane; LDS dest = uniform base + lane*16
static __device__ __forceinline__ void gload_lds16(const unsigned short* g, unsigned short* l) {
    __builtin_amdgcn_global_load_lds(
        (const __attribute__((address_space(1))) void*)g,
        (__attribute__((address_space(3))) void*)l,
        16, 0, 0);
}

// ---------------- degree histogram ----------------
__global__ void k_hist(const int* __restrict__ src, const int* __restrict__ dst,
                       int* __restrict__ outdeg, int* __restrict__ indeg) {
    int i = blockIdx.x * blockDim.x + threadIdx.x;
    if (i >= RR * EE) return;
    int r = i / EE;
    atomicAdd(&outdeg[r * NN + src[i]], 1);
    atomicAdd(&indeg[r * NN + dst[i]], 1);
}

// ---------------- norms: in-place int degree -> float rsqrt ----------------
__global__ void k_norms(int* __restrict__ outdeg, int* __restrict__ indeg) {
    int i = blockIdx.x * blockDim.x + threadIdx.x;
    if (i >= RR * NN) return;
    int od = outdeg[i];
    int id = indeg[i];
    ((float*)outdeg)[i] = od > 0 ? rsqrtf((float)od) : 0.f;
    ((float*)indeg)[i]  = id > 0 ? rsqrtf((float)id) : 0.f;
}

// ---------------- parallel scan: phase A (per-block sums) ----------------
__global__ void k_scanA(const int* __restrict__ indeg, int* __restrict__ bsum) {
    int r = blockIdx.y;
    int i = blockIdx.x * 256 + threadIdx.x;
    int v = (i < NN) ? indeg[(size_t)r * NN + i] : 0;
    #pragma unroll
    for (int d = 32; d > 0; d >>= 1) v += __shfl_down(v, d, 64);
    __shared__ int ws4[4];
    if ((threadIdx.x & 63) == 0) ws4[threadIdx.x >> 6] = v;
    __syncthreads();
    if (threadIdx.x == 0) bsum[r * SCB + blockIdx.x] = ws4[0] + ws4[1] + ws4[2] + ws4[3];
}

// ---------------- phase B: exclusive scan of SCB block sums per relation ----------------
__global__ void k_scanB(int* __restrict__ bsum, int* __restrict__ offs) {
    int r = blockIdx.x;
    int t = threadIdx.x;
    int v = (t < SCB) ? bsum[r * SCB + t] : 0;
    int lane = t & 63, wid = t >> 6;
    int sv = v;
    #pragma unroll
    for (int d = 1; d < 64; d <<= 1) {
        int u = __shfl_up(sv, d, 64);
        if (lane >= d) sv += u;
    }
    __shared__ int wsum[4];
    if (lane == 63) wsum[wid] = sv;
    __syncthreads();
    int add = 0;
    for (int x = 0; x < wid; x++) add += wsum[x];
    int incl = sv + add;
    if (t < SCB) bsum[r * SCB + t] = incl - v;
    if (t == 255) offs[(size_t)r * (NN + 1) + NN] = incl;  // grand total
}

// ---------------- phase C: intra-block exclusive scan + base ----------------
__global__ void k_scanC(const int* __restrict__ indeg, const int* __restrict__ bsum,
                        int* __restrict__ offs) {
    int r = blockIdx.y;
    int i = blockIdx.x * 256 + threadIdx.x;
    int v = (i < NN) ? indeg[(size_t)r * NN + i] : 0;
    int lane = threadIdx.x & 63, wid = threadIdx.x >> 6;
    int sv = v;
    #pragma unroll
    for (int d = 1; d < 64; d <<= 1) {
        int u = __shfl_up(sv, d, 64);
        if (lane >= d) sv += u;
    }
    __shared__ int wsum[4];
    if (lane == 63) wsum[wid] = sv;
    __syncthreads();
    int add = bsum[r * SCB + blockIdx.x];
    for (int x = 0; x < wid; x++) add += wsum[x];
    if (i < NN) offs[(size_t)r * (NN + 1) + i] = sv - v + add;
}

// ---------------- fill CSR ----------------
__global__ void k_fill(const int* __restrict__ src, const int* __restrict__ dst,
                       const int* __restrict__ offs, int* __restrict__ cursor,
                       int* __restrict__ csr) {
    int i = blockIdx.x * blockDim.x + threadIdx.x;
    if (i >= RR * EE) return;
    int r = i / EE;
    int d = dst[i];
    int pos = offs[r * (NN + 1) + d] + atomicAdd(&cursor[r * NN + d], 1);
    csr[(size_t)r * EE + pos] = src[i];
}

// ---------------- bias sums over relations ----------------
__global__ void k_bsum(const float* __restrict__ b2a, const float* __restrict__ b2b,
                       const float* __restrict__ b3a, const float* __restrict__ b3b,
                       float* __restrict__ bs) {
    int j = threadIdx.x;  // 256
    float s = 0.f;
    for (int r = 0; r < RR; r++) s += b2a[r * 256 + j];
    bs[j] = s;
    if (j < 128) {
        s = 0.f;
        for (int r = 0; r < RR; r++) s += b2b[r * 128 + j];
        bs[256 + j] = s;
    }
    s = 0.f;
    for (int r = 0; r < RR; r++) s += b3a[r * 256 + j];
    bs[512 + j] = s;
    if (j < 128) {
        s = 0.f;
        for (int r = 0; r < RR; r++) s += b3b[r * 128 + j];
        bs[768 + j] = s;
    }
}

// ---------------- fp32 -> bf16 elementwise cast ----------------
__global__ void k_cast(const float* __restrict__ x, unsigned short* __restrict__ y, int total) {
    int i = blockIdx.x * blockDim.x + threadIdx.x;
    if (i < total) y[i] = f2bf(x[i]);
}

// ---------------- weights: W[R,K0,Nout] -> WT[Nout][R*Kpad] bf16 ----------------
__global__ void k_wt(const float* __restrict__ W, unsigned short* __restrict__ WT,
                     int K0, int Kpad, int Nout) {
    int i = blockIdx.x * blockDim.x + threadIdx.x;
    int total = Nout * RR * Kpad;
    if (i >= total) return;
    int n = i / (RR * Kpad);
    int rem = i - n * (RR * Kpad);
    int r = rem / Kpad;
    int k = rem - r * Kpad;
    float v = (k < K0) ? W[((size_t)r * K0 + k) * Nout + n] : 0.f;
    WT[i] = f2bf(v);
}

// ---------------- aggregation ----------------
__global__ void k_agg(const unsigned short* __restrict__ xb, int xstride, int din4, int nch,
                      const int* __restrict__ csr, const int* __restrict__ offs,
                      const float* __restrict__ ns, const float* __restrict__ nd,
                      int rbase, int nbase, unsigned short* __restrict__ Y,
                      int Kpad, int ystride) {
    int n = nbase + blockIdx.x;
    int r = rbase + blockIdx.y;
    int j = threadIdx.x;
    if (j >= nch) return;
    int o0 = offs[r * (NN + 1) + n];
    int o1 = offs[r * (NN + 1) + n + 1];
    float ndv = nd[(size_t)r * NN + n];
    const int* cs = csr + (size_t)r * EE;
    float a0 = 0.f, a1 = 0.f, a2 = 0.f, a3 = 0.f;
    if (j < din4) {
        for (int e = o0; e < o1; e++) {
            int s = cs[e];
            float w = ns[(size_t)r * NN + s];
            ushort4 v = *(const ushort4*)(xb + (size_t)s * xstride + j * 4);
            a0 += w * bf2f(v.x); a1 += w * bf2f(v.y);
            a2 += w * bf2f(v.z); a3 += w * bf2f(v.w);
        }
    }
    ushort4 o;
    o.x = f2bf(a0 * ndv); o.y = f2bf(a1 * ndv);
    o.z = f2bf(a2 * ndv); o.w = f2bf(a3 * ndv);
    *(ushort4*)(Y + (size_t)blockIdx.x * ystride + (size_t)blockIdx.y * Kpad + j * 4) = o;
}

// ---------------- bf16 MFMA GEMM, async-LDS staged, XOR-swizzled ----------------
// Tile 128 x (TN*32). A [M x K] bf16 (lda), BT [Nout x K] bf16 (ldb).
// flags: 1=addbias, 2=accum(read Cin fp32), 4=relu, 8=out bf16 (else fp32)
template<int TN>
__global__ __launch_bounds__(256) void k_gemm_bf(
        const unsigned short* __restrict__ A, int lda,
        const unsigned short* __restrict__ BT, int ldb,
        const float* __restrict__ bias,
        const float* __restrict__ Cin, int ldcin,
        void* __restrict__ Cout, int ldc,
        int M, int K, int flags) {
    constexpr int BN = TN * 32;
    __shared__ unsigned short As[128 * 64];
    __shared__ unsigned short Bs[BN * 64];
    int m0 = blockIdx.x * 128;
    int n0 = blockIdx.y * BN;
    int t = threadIdx.x;
    int w = t >> 6, l = t & 63;
    int qm = (w >> 1) * 64, qn = (w & 1) * (TN * 16);
    int lr = l & 15, lg = l >> 4;
    int lrow = l >> 3;            // row within 8-row segment
    int lch  = (l & 7) ^ lrow;    // swizzled source chunk (8 bf16 each)

    floatx4 acc[4][TN];
    #pragma unroll
    for (int a = 0; a < 4; a++)
        #pragma unroll
        for (int b = 0; b < TN; b++)
            acc[a][b] = (floatx4){0.f, 0.f, 0.f, 0.f};

    for (int k0 = 0; k0 < K; k0 += 64) {
        #pragma unroll
        for (int j = 0; j < 4; j++) {
            int seg = w * 4 + j;              // 16 segments x 8 rows = 128 rows
            int gr = m0 + seg * 8 + lrow; if (gr > M - 1) gr = M - 1;
            gload_lds16(A + (size_t)gr * lda + k0 + lch * 8, &As[seg * 512]);
        }
        #pragma unroll
        for (int j = 0; j < TN; j++) {
            int seg = w * TN + j;             // BN/8 segments
            int row = n0 + seg * 8 + lrow;
            gload_lds16(BT + (size_t)row * ldb + k0 + lch * 8, &Bs[seg * 512]);
        }
        __syncthreads();
        #pragma unroll
        for (int ks = 0; ks < 2; ks++) {
            int slot = ((ks * 4 + lg) ^ (lr & 7)) * 8;
            short8 af[4], bf[TN];
            #pragma unroll
            for (int i = 0; i < 4; i++)
                af[i] = *(const short8*)&As[(qm + i * 16 + lr) * 64 + slot];
            #pragma unroll
            for (int i = 0; i < TN; i++)
                bf[i] = *(const short8*)&Bs[(qn + i * 16 + lr) * 64 + slot];
            #pragma unroll
            for (int tm = 0; tm < 4; tm++)
                #pragma unroll
                for (int tn = 0; tn < TN; tn++)
                    acc[tm][tn] = __builtin_amdgcn_mfma_f32_16x16x32_bf16(
                        af[tm], bf[tn], acc[tm][tn], 0, 0, 0);
        }
        __syncthreads();
    }

    int addbias = flags & 1, accum = flags & 2, relu = flags & 4, outbf = flags & 8;
    #pragma unroll
    for (int tm = 0; tm < 4; tm++) {
        int rbase = m0 + qm + tm * 16 + lg * 4;
        #pragma unroll
        for (int reg = 0; reg < 4; reg++) {
            int row = rbase + reg;
            if (row >= M) continue;
            #pragma unroll
            for (int tn = 0; tn < TN; tn++) {
                int col = n0 + qn + tn * 16 + lr;
                float v = acc[tm][tn][reg];
                if (addbias) v += bias[col];
                if (accum) v += Cin[(size_t)row * ldcin + col];
                if (relu) v = fmaxf(v, 0.f);
                if (outbf) ((unsigned short*)Cout)[(size_t)row * ldc + col] = f2bf(v);
                else       ((float*)Cout)[(size_t)row * ldc + col] = v;
            }
        }
    }
}

// ---------------- fused decoder weights ----------------
__global__ void k_mcat(const float* __restrict__ Wp1, const float* __restrict__ Wp2,
                       const float* __restrict__ bp1, const float* __restrict__ bp2,
                       float* __restrict__ Mcat, float* __restrict__ cvec) {
    int t = blockIdx.x * blockDim.x + threadIdx.x;
    if (t < 4096) {
        int i = t >> 4, j = t & 15;
        int half = j >> 3, jj = j & 7;
        const float* wrow = Wp1 + (size_t)(half * 256 + i) * 256;
        float s = 0.f;
        for (int k = 0; k < 256; k++) s += wrow[k] * Wp2[k * 8 + jj];
        Mcat[i * 16 + j] = s;
    } else if (t < 4096 + 8) {
        int j = t - 4096;
        float s = bp2[j];
        for (int k = 0; k < 256; k++) s += bp1[k] * Wp2[k * 8 + j];
        cvec[j] = s;
    }
}

// ---------------- AB = feat @ Mcat  [N x 16] (float4 loads) ----------------
__global__ void k_ab(const float* __restrict__ feat, const float* __restrict__ Mcat,
                     float* __restrict__ AB) {
    __shared__ float Ms[4096];
    int t = threadIdx.x;
    for (int i = t; i < 4096; i += 256) Ms[i] = Mcat[i];
    __syncthreads();
    int n = blockIdx.x * 16 + (t >> 4);
    int c = t & 15;
    const float4* fr = (const float4*)(feat + (size_t)n * 256);
    float s = 0.f;
    #pragma unroll 8
    for (int k4 = 0; k4 < 64; k4++) {
        float4 v = fr[k4];
        s += v.x * Ms[(k4 * 4 + 0) * 16 + c] + v.y * Ms[(k4 * 4 + 1) * 16 + c]
           + v.z * Ms[(k4 * 4 + 2) * 16 + c] + v.w * Ms[(k4 * 4 + 3) * 16 + c];
    }
    AB[(size_t)n * 16 + c] = s;
}

// ---------------- per-edge decoder ----------------
__global__ void k_dec(const int* __restrict__ dsrc, const int* __restrict__ ddst,
                      const float* __restrict__ AB, const float* __restrict__ cvec,
                      float* __restrict__ out) {
    int i = blockIdx.x * blockDim.x + threadIdx.x;
    if (i >= EDD * 8) return;
    int e = i >> 3, k = i & 7;
    out[i] = AB[dsrc[e] * 16 + k] + AB[ddst[e] * 16 + 8 + k] + cvec[k];
}

extern "C" void kernel_launch(void* const* d_in, const int* in_sizes, int n_in,
                              void* d_out, int out_size, void* d_ws, size_t ws_size,
                              hipStream_t stream) {
    const float* x2  = (const float*)d_in[0];
    const float* x3  = (const float*)d_in[1];
    const int*   src = (const int*)d_in[2];
    const int*   dst = (const int*)d_in[3];
    const int*   dsrc = (const int*)d_in[4];
    const int*   ddst = (const int*)d_in[5];
    const float* W2a = (const float*)d_in[6];
    const float* b2a = (const float*)d_in[7];
    const float* W2b = (const float*)d_in[8];
    const float* b2b = (const float*)d_in[9];
    const float* W3a = (const float*)d_in[10];
    const float* b3a = (const float*)d_in[11];
    const float* W3b = (const float*)d_in[12];
    const float* b3b = (const float*)d_in[13];
    const float* Wp1 = (const float*)d_in[14];
    const float* bp1 = (const float*)d_in[15];
    const float* Wp2 = (const float*)d_in[16];
    const float* bp2 = (const float*)d_in[17];
    float* out = (float*)d_out;

    // ---- workspace layout (~181.8 MB) ----
    char* ws = (char*)d_ws;
    size_t off = 0;
    auto alloc = [&](size_t nbytes) {
        char* p = ws + off;
        off += nbytes;
        off = (off + 255) & ~(size_t)255;
        return p;
    };
    float* ns   = (float*)alloc((size_t)RR * NN * 4);        // aliases outdeg
    float* nd   = (float*)alloc((size_t)RR * NN * 4);        // aliases indeg
    int*   offs = (int*)alloc((size_t)RR * (NN + 1) * 4);
    int*   csr  = (int*)alloc((size_t)RR * EE * 4);
    unsigned short* XH   = (unsigned short*)alloc((size_t)NN * 300 * 2);  // x2b then x3b
    unsigned short* hbuf = (unsigned short*)alloc((size_t)NN * 256 * 2);  // layer-a out; AB aliases
    unsigned short* WT2a = (unsigned short*)alloc((size_t)256 * 2048 * 2);
    unsigned short* WT2b = (unsigned short*)alloc((size_t)128 * 2048 * 2);
    unsigned short* WT3a = (unsigned short*)alloc((size_t)256 * 2432 * 2);
    unsigned short* WT3b = (unsigned short*)alloc((size_t)128 * 2048 * 2);
    unsigned short* Y    = (unsigned short*)alloc((size_t)12500 * 2432 * 2);  // cursor aliases head
    float* feat  = (float*)alloc((size_t)NN * 256 * 4);
    float* bsums = (float*)alloc(1024 * 4);
    float* Mcat  = (float*)alloc(4096 * 4);
    float* cvec  = (float*)alloc(64 * 4);
    int*   bsum  = (int*)alloc((size_t)RR * SCB * 4);

    int*   outdeg = (int*)ns;
    int*   indeg  = (int*)nd;
    int*   cursor = (int*)Y;       // only live during k_fill (before any Y use)
    float* AB     = (float*)hbuf;  // only live after last hbuf read

    // ---- graph prep ----
    hipMemsetAsync(outdeg, 0, (size_t)RR * NN * 4, stream);
    hipMemsetAsync(indeg,  0, (size_t)RR * NN * 4, stream);
    hipMemsetAsync(cursor, 0, (size_t)RR * NN * 4, stream);

    int histBlocks = (RR * EE + 255) / 256;
    k_hist<<<histBlocks, 256, 0, stream>>>(src, dst, outdeg, indeg);
    k_scanA<<<dim3(SCB, RR), 256, 0, stream>>>(indeg, bsum);
    k_scanB<<<RR, 256, 0, stream>>>(bsum, offs);
    k_scanC<<<dim3(SCB, RR), 256, 0, stream>>>(indeg, bsum, offs);
    k_norms<<<(RR * NN + 255) / 256, 256, 0, stream>>>(outdeg, indeg);
    k_fill<<<histBlocks, 256, 0, stream>>>(src, dst, offs, cursor, csr);
    k_bsum<<<1, 256, 0, stream>>>(b2a, b2b, b3a, b3b, bsums);
    k_mcat<<<17, 256, 0, stream>>>(Wp1, Wp2, bp1, bp2, Mcat, cvec);

    k_cast<<<(NN * 256 + 255) / 256, 256, 0, stream>>>(x2, XH, NN * 256);
    k_wt<<<(256 * RR * 256 + 255) / 256, 256, 0, stream>>>(W2a, WT2a, 256, 256, 256);
    k_wt<<<(128 * RR * 256 + 255) / 256, 256, 0, stream>>>(W2b, WT2b, 256, 256, 128);
    k_wt<<<(256 * RR * 304 + 255) / 256, 256, 0, stream>>>(W3a, WT3a, 300, 304, 256);
    k_wt<<<(128 * RR * 256 + 255) / 256, 256, 0, stream>>>(W3b, WT3b, 256, 256, 128);

    const int CH = 12500;                  // node chunk for layer-a (4 chunks)
    dim3 gChunkA((CH + 127) / 128, 4);     // layer-a GEMM: BN=64, Nout=256
    dim3 gFullB((NN + 127) / 128, 1);      // layer-b GEMM: BN=128, Nout=128

    // ---- layer 2a: hbuf = relu(sum_r agg_r(x2b) @ W2a_r + b) ----
    for (int c = 0; c < 4; c++) {
        int nb = c * CH;
        k_agg<<<dim3(CH, 8), 64, 0, stream>>>(XH, 256, 64, 64, csr, offs, ns, nd,
                                              0, nb, Y, 256, 2048);
        k_gemm_bf<2><<<gChunkA, 256, 0, stream>>>(Y, 2048, WT2a, 2048, bsums + 0,
                                                  feat, 256, (void*)(hbuf + (size_t)nb * 256), 256,
                                                  CH, 2048, 1 | 4 | 8);
    }
    // ---- layer 2b: feat[:, :128] ----
    for (int p = 0; p < 4; p++) {
        k_agg<<<dim3(NN, 2), 64, 0, stream>>>(hbuf, 256, 64, 64, csr, offs, ns, nd,
                                              p * 2, 0, Y, 256, 512);
        k_gemm_bf<4><<<gFullB, 256, 0, stream>>>(Y, 512, WT2b + (size_t)p * 512, 2048,
                                                 bsums + 256, feat, 256, (void*)feat, 256,
                                                 NN, 512, (p == 0) ? 1 : 2);
    }
    // ---- layer 3a (x3: din 300) ----
    k_cast<<<(NN * 300 + 255) / 256, 256, 0, stream>>>(x3, XH, NN * 300);
    for (int c = 0; c < 4; c++) {
        int nb = c * CH;
        k_agg<<<dim3(CH, 8), 128, 0, stream>>>(XH, 300, 75, 76, csr, offs, ns, nd,
                                               0, nb, Y, 304, 2432);
        k_gemm_bf<2><<<gChunkA, 256, 0, stream>>>(Y, 2432, WT3a, 2432, bsums + 512,
                                                  feat, 256, (void*)(hbuf + (size_t)nb * 256), 256,
                                                  CH, 2432, 1 | 4 | 8);
    }
    // ---- layer 3b: feat[:, 128:] ----
    for (int p = 0; p < 4; p++) {
        k_agg<<<dim3(NN, 2), 64, 0, stream>>>(hbuf, 256, 64, 64, csr, offs, ns, nd,
                                              p * 2, 0, Y, 256, 512);
        k_gemm_bf<4><<<gFullB, 256, 0, stream>>>(Y, 512, WT3b + (size_t)p * 512, 2048,
                                                 bsums + 768, feat + 128, 256, (void*)(feat + 128), 256,
                                                 NN, 512, (p == 0) ? 1 : 2);
    }

    // ---- decoder ----
    k_ab<<<NN / 16, 256, 0, stream>>>(feat, Mcat, AB);
    k_dec<<<(EDD * 8 + 255) / 256, 256, 0, stream>>>(dsrc, ddst, AB, cvec, out);
}